// Round 12
// baseline (52.800 us; speedup 1.0000x reference)
//
#include <hip/hip_runtime.h>

#define HWD    48400          // 220*220
#define PATCHD 75
#define NPOS   96800          // 2 * HWD

typedef __attribute__((ext_vector_type(8))) _Float16 f16x8;
typedef __attribute__((ext_vector_type(2))) __fp16   h16x2;   // cvt_pkrtz return type
typedef __attribute__((ext_vector_type(4))) float    f32x4;

union U2 { h16x2 h; unsigned u; };
union UF { unsigned u[4]; f16x8 v; };

// ---------------------------------------------------------------------------
// Table build, FRAGMENT-MAJOR layout (unchanged from round 10):
//   tbl[((t*4 + g)*16 + c)*8 + j],  t = role*3 + s,  k = 32s + 8g + j
//   role 0 = exp(k1), 1 = k1*exp(k1), 2 = exp(k2), 3 = k2*exp(k2); k>=75 -> 0
// ---------------------------------------------------------------------------
__global__ void smorph_build_tables(const float* __restrict__ k1,
                                    const float* __restrict__ k2,
                                    _Float16* __restrict__ tbl)
{
    int i = (int)blockIdx.x * 256 + (int)threadIdx.x;   // 6144 entries
    if (i >= 4 * 3 * 4 * 16 * 8) return;
    const int j = i & 7;
    const int c = (i >> 3) & 15;
    const int g = (i >> 7) & 3;
    const int t = i >> 9;          // 0..11 = role*3 + s
    const int s = t % 3;
    const int r = t / 3;
    const int k = 32 * s + 8 * g + j;
    float val = 0.f;
    if (k < PATCHD) {
        const float* kw = (r < 2) ? k1 : k2;
        const float w = kw[k * 16 + c];
        const float e = __expf(w);
        val = (r & 1) ? (w * e) : e;
    }
    tbl[i] = (_Float16)val;
}

// ---------------------------------------------------------------------------
// INSTRUMENTATION VARIANT of the round-10 body: opaque nrep repeats
// (rep_off==0 at runtime) so rocprof's top-5 exposes this kernel's counters.
// Stores write identical values every repeat -> deterministic, harness-safe.
// ---------------------------------------------------------------------------
__global__ __launch_bounds__(256, 4)
void smorph_mfma6r(const float* __restrict__ x,
                   const _Float16* __restrict__ tbl,
                   const float* __restrict__ bias,
                   float* __restrict__ out,
                   int nrep, long rep_off)
{
    const int tid = (int)threadIdx.x;
    const int l   = tid & 63;
    const int w   = tid >> 6;
    const int g   = l >> 4;         // k-subgroup 0..3
    const int c   = l & 15;         // channel lane (A) / position lane (B,D)
    const int p0  = (int)blockIdx.x * 64 + w * 16;
    if (p0 >= NPOS) return;         // no barriers anywhere -> safe
    const int b   = (p0 >= HWD) ? 1 : 0;   // HWD % 16 == 0: no straddle
    const int hw0 = p0 - b * HWD;

    const float* xb0 = x + (size_t)b * PATCHD * HWD + hw0 + c;
    const int fbase = g * 16 + c;   // lane-linear within each 64-frag group

    for (int rep = 0; rep < nrep; ++rep) {
        const float* xb = xb0 + rep * rep_off;              // opaque: defeats CSE
        const f16x8* tf = (const f16x8*)(tbl + rep * rep_off);

        // ---- issue ALL x loads first: 3 steps x 8, clamped to k=74 ----
        float xv[3][8];
        #pragma unroll
        for (int s = 0; s < 3; ++s)
            #pragma unroll
            for (int j = 0; j < 8; ++j) {
                int k = 32 * s + 8 * g + j;
                k = (k > PATCHD - 1) ? (PATCHD - 1) : k;
                xv[s][j] = xb[(size_t)k * HWD];
            }

        f32x4 aN1 = {0.f,0.f,0.f,0.f}, aD1 = {0.f,0.f,0.f,0.f};
        f32x4 aN2 = {0.f,0.f,0.f,0.f}, aD2 = {0.f,0.f,0.f,0.f};

        #pragma unroll
        for (int s = 0; s < 3; ++s) {
            const f16x8 a1f = tf[(0 * 3 + s) * 64 + fbase];
            const f16x8 b1f = tf[(1 * 3 + s) * 64 + fbase];
            const f16x8 a2f = tf[(2 * 3 + s) * 64 + fbase];
            const f16x8 b2f = tf[(3 * 3 + s) * 64 + fbase];

            float E[8], R[8];
            #pragma unroll
            for (int j = 0; j < 8; ++j) {
                E[j] = __expf(xv[s][j]);
                R[j] = __expf(-xv[s][j]);
            }

            UF fEx, fE, fRx, fR;
            #pragma unroll
            for (int jp = 0; jp < 4; ++jp) {
                const float x0 = xv[s][2*jp], x1 = xv[s][2*jp+1];
                U2 q;
                q.h = __builtin_amdgcn_cvt_pkrtz(E[2*jp] * x0,  E[2*jp+1] * x1);  fEx.u[jp] = q.u;
                q.h = __builtin_amdgcn_cvt_pkrtz(E[2*jp],       E[2*jp+1]);       fE.u[jp]  = q.u;
                q.h = __builtin_amdgcn_cvt_pkrtz(-R[2*jp] * x0, -R[2*jp+1] * x1); fRx.u[jp] = q.u;
                q.h = __builtin_amdgcn_cvt_pkrtz(R[2*jp],       R[2*jp+1]);       fR.u[jp]  = q.u;
            }

            aN1 = __builtin_amdgcn_mfma_f32_16x16x32_f16(a1f, fEx.v, aN1, 0, 0, 0);
            aN1 = __builtin_amdgcn_mfma_f32_16x16x32_f16(b1f, fE.v,  aN1, 0, 0, 0);
            aD1 = __builtin_amdgcn_mfma_f32_16x16x32_f16(a1f, fE.v,  aD1, 0, 0, 0);
            aN2 = __builtin_amdgcn_mfma_f32_16x16x32_f16(a2f, fRx.v, aN2, 0, 0, 0);
            aN2 = __builtin_amdgcn_mfma_f32_16x16x32_f16(b2f, fR.v,  aN2, 0, 0, 0);
            aD2 = __builtin_amdgcn_mfma_f32_16x16x32_f16(a2f, fR.v,  aD2, 0, 0, 0);
        }

        const float4 bsv = *(const float4*)(bias + 4 * g);
        float* ob = out + ((size_t)(b * 16 + 4 * g)) * HWD + hw0 + c;
        ob[0 * (size_t)HWD] = aN1[0] * __builtin_amdgcn_rcpf(aD1[0]) + aN2[0] * __builtin_amdgcn_rcpf(aD2[0]) + bsv.x;
        ob[1 * (size_t)HWD] = aN1[1] * __builtin_amdgcn_rcpf(aD1[1]) + aN2[1] * __builtin_amdgcn_rcpf(aD2[1]) + bsv.y;
        ob[2 * (size_t)HWD] = aN1[2] * __builtin_amdgcn_rcpf(aD1[2]) + aN2[2] * __builtin_amdgcn_rcpf(aD2[2]) + bsv.z;
        ob[3 * (size_t)HWD] = aN1[3] * __builtin_amdgcn_rcpf(aD1[3]) + aN2[3] * __builtin_amdgcn_rcpf(aD2[3]) + bsv.w;
    }
}

extern "C" void kernel_launch(void* const* d_in, const int* in_sizes, int n_in,
                              void* d_out, int out_size, void* d_ws, size_t ws_size,
                              hipStream_t stream)
{
    const float* x    = (const float*)d_in[0];
    const float* k1   = (const float*)d_in[1];
    const float* k2   = (const float*)d_in[2];
    const float* bias = (const float*)d_in[3];
    float* out = (float*)d_out;
    _Float16* tbl = (_Float16*)d_ws;     // 12 KB, fragment-major

    smorph_build_tables<<<(4 * 3 * 4 * 16 * 8 + 255) / 256, 256, 0, stream>>>(k1, k2, tbl);
    // nrep=10, rep_off=0: push dur above the ~40us poison fills -> counters visible
    smorph_mfma6r<<<(NPOS + 63) / 64, 256, 0, stream>>>(x, tbl, bias, out, 10, 0L);
}

// Round 13
// 17.510 us; speedup vs baseline: 3.0154x; 3.0154x over previous
//
#include <hip/hip_runtime.h>

#define HWD    48400          // 220*220
#define PATCHD 75
#define NPOS   96800          // 2 * HWD
#define LOG2E  1.44269504088896340736f

typedef __attribute__((ext_vector_type(8))) _Float16 f16x8;
typedef __attribute__((ext_vector_type(2))) __fp16   h16x2;   // cvt_pkrtz return type
typedef __attribute__((ext_vector_type(4))) float    f32x4;

union U2 { h16x2 h; unsigned u; };
union UF { unsigned u[4]; f16x8 v; };

// ---------------------------------------------------------------------------
// Table build, FRAGMENT-MAJOR layout (unchanged from round 10):
//   tbl[((t*4 + g)*16 + c)*8 + j],  t = role*3 + s,  k = 32s + 8g + j
//   role 0 = exp(k1), 1 = k1*exp(k1), 2 = exp(k2), 3 = k2*exp(k2); k>=75 -> 0
// ---------------------------------------------------------------------------
__global__ void smorph_build_tables(const float* __restrict__ k1,
                                    const float* __restrict__ k2,
                                    _Float16* __restrict__ tbl)
{
    int i = (int)blockIdx.x * 256 + (int)threadIdx.x;   // 6144 entries
    if (i >= 4 * 3 * 4 * 16 * 8) return;
    const int j = i & 7;
    const int c = (i >> 3) & 15;
    const int g = (i >> 7) & 3;
    const int t = i >> 9;          // 0..11 = role*3 + s
    const int s = t % 3;
    const int r = t / 3;
    const int k = 32 * s + 8 * g + j;
    float val = 0.f;
    if (k < PATCHD) {
        const float* kw = (r < 2) ? k1 : k2;
        const float w = kw[k * 16 + c];
        const float e = __expf(w);
        val = (r & 1) ? (w * e) : e;
    }
    tbl[i] = (_Float16)val;
}

// ---------------------------------------------------------------------------
// Main: each wave owns TWO adjacent 16-pos MFMA tiles (32 consecutive
// positions). All 60 loads (12 table frags + 48 x) issue up front; tile B's
// latency drains under tile A's compute. Grid 757 = whole grid co-resident.
// ---------------------------------------------------------------------------
__global__ __launch_bounds__(256, 3)
void smorph_mfma8(const float* __restrict__ x,
                  const _Float16* __restrict__ tbl,
                  const float* __restrict__ bias,
                  float* __restrict__ out)
{
    const int tid = (int)threadIdx.x;
    const int l   = tid & 63;
    const int w   = tid >> 6;
    const int g   = l >> 4;         // k-subgroup 0..3
    const int c   = l & 15;         // channel lane (A-op) / position lane (B-op, D)

    int bb = (int)blockIdx.x * 128;
    if (bb > NPOS - 128) bb = NPOS - 128;    // clamp: duplicate identical stores
    const int pA = bb + w * 32;
    const int pB = pA + 16;
    const int bA = (pA >= HWD) ? 1 : 0;      // HWD % 16 == 0: tiles never straddle
    const int bB = (pB >= HWD) ? 1 : 0;
    const int hwA = pA - bA * HWD;
    const int hwB = pB - bB * HWD;
    const float* xbA = x + (size_t)bA * PATCHD * HWD + hwA + c;
    const float* xbB = x + (size_t)bB * PATCHD * HWD + hwB + c;

    // ---- table fragments first (12 coalesced dwordx4, L1/L2-hot) ----
    const f16x8* tf = (const f16x8*)tbl;
    const int fbase = g * 16 + c;
    f16x8 Tf[12];
    #pragma unroll
    for (int t = 0; t < 12; ++t) Tf[t] = tf[t * 64 + fbase];

    // ---- all x loads up front: 2 tiles x 24 (k clamped; zero table rows kill pad) ----
    float xvA[24], xvB[24];
    #pragma unroll
    for (int s = 0; s < 3; ++s)
        #pragma unroll
        for (int j = 0; j < 8; ++j) {
            int k = 32 * s + 8 * g + j;
            k = (k > PATCHD - 1) ? (PATCHD - 1) : k;
            xvA[s * 8 + j] = xbA[(size_t)k * HWD];
            xvB[s * 8 + j] = xbB[(size_t)k * HWD];
        }

    f32x4 aN1A = {0.f,0.f,0.f,0.f}, aD1A = {0.f,0.f,0.f,0.f};
    f32x4 aN2A = {0.f,0.f,0.f,0.f}, aD2A = {0.f,0.f,0.f,0.f};
    f32x4 aN1B = {0.f,0.f,0.f,0.f}, aD1B = {0.f,0.f,0.f,0.f};
    f32x4 aN2B = {0.f,0.f,0.f,0.f}, aD2B = {0.f,0.f,0.f,0.f};

    // per-s compute for one tile: E=exp2(t), R=exp2(-t) (free neg modifier)
    #define COMP(src, aN1, aD1, aN2, aD2)                                     \
        _Pragma("unroll")                                                     \
        for (int s = 0; s < 3; ++s) {                                         \
            float E[8], R[8];                                                 \
            _Pragma("unroll")                                                 \
            for (int j = 0; j < 8; ++j) {                                     \
                const float t_ = (src)[s * 8 + j] * LOG2E;                    \
                E[j] = __builtin_amdgcn_exp2f(t_);                            \
                R[j] = __builtin_amdgcn_exp2f(-t_);                           \
            }                                                                 \
            UF fEx, fE, fRx, fR;                                              \
            _Pragma("unroll")                                                 \
            for (int jp = 0; jp < 4; ++jp) {                                  \
                const float x0 = (src)[s * 8 + 2 * jp];                       \
                const float x1 = (src)[s * 8 + 2 * jp + 1];                   \
                U2 q;                                                         \
                q.h = __builtin_amdgcn_cvt_pkrtz(E[2*jp] * x0,  E[2*jp+1] * x1);  fEx.u[jp] = q.u; \
                q.h = __builtin_amdgcn_cvt_pkrtz(E[2*jp],       E[2*jp+1]);       fE.u[jp]  = q.u; \
                q.h = __builtin_amdgcn_cvt_pkrtz(-R[2*jp] * x0, -R[2*jp+1] * x1); fRx.u[jp] = q.u; \
                q.h = __builtin_amdgcn_cvt_pkrtz(R[2*jp],       R[2*jp+1]);       fR.u[jp]  = q.u; \
            }                                                                 \
            aN1 = __builtin_amdgcn_mfma_f32_16x16x32_f16(Tf[0 + s], fEx.v, aN1, 0, 0, 0); \
            aN1 = __builtin_amdgcn_mfma_f32_16x16x32_f16(Tf[3 + s], fE.v,  aN1, 0, 0, 0); \
            aD1 = __builtin_amdgcn_mfma_f32_16x16x32_f16(Tf[0 + s], fE.v,  aD1, 0, 0, 0); \
            aN2 = __builtin_amdgcn_mfma_f32_16x16x32_f16(Tf[6 + s], fRx.v, aN2, 0, 0, 0); \
            aN2 = __builtin_amdgcn_mfma_f32_16x16x32_f16(Tf[9 + s], fR.v,  aN2, 0, 0, 0); \
            aD2 = __builtin_amdgcn_mfma_f32_16x16x32_f16(Tf[6 + s], fR.v,  aD2, 0, 0, 0); \
        }

    COMP(xvA, aN1A, aD1A, aN2A, aD2A)      // B's loads drain underneath
    COMP(xvB, aN1B, aD1B, aN2B, aD2B)
    #undef COMP

    // ---- epilogue: y = num1/den1 + num2/den2 + bias ----
    const float4 bsv = *(const float4*)(bias + 4 * g);
    float* obA = out + ((size_t)(bA * 16 + 4 * g)) * HWD + hwA + c;
    float* obB = out + ((size_t)(bB * 16 + 4 * g)) * HWD + hwB + c;
    #pragma unroll
    for (int r = 0; r < 4; ++r) {
        const float bsr = (r == 0) ? bsv.x : (r == 1) ? bsv.y : (r == 2) ? bsv.z : bsv.w;
        obA[(size_t)r * HWD] = aN1A[r] * __builtin_amdgcn_rcpf(aD1A[r])
                             + aN2A[r] * __builtin_amdgcn_rcpf(aD2A[r]) + bsr;
        obB[(size_t)r * HWD] = aN1B[r] * __builtin_amdgcn_rcpf(aD1B[r])
                             + aN2B[r] * __builtin_amdgcn_rcpf(aD2B[r]) + bsr;
    }
}

extern "C" void kernel_launch(void* const* d_in, const int* in_sizes, int n_in,
                              void* d_out, int out_size, void* d_ws, size_t ws_size,
                              hipStream_t stream)
{
    const float* x    = (const float*)d_in[0];
    const float* k1   = (const float*)d_in[1];
    const float* k2   = (const float*)d_in[2];
    const float* bias = (const float*)d_in[3];
    float* out = (float*)d_out;
    _Float16* tbl = (_Float16*)d_ws;     // 12 KB, fragment-major

    smorph_build_tables<<<(4 * 3 * 4 * 16 * 8 + 255) / 256, 256, 0, stream>>>(k1, k2, tbl);
    smorph_mfma8<<<(NPOS + 127) / 128, 256, 0, stream>>>(x, tbl, bias, out);
}